// Round 1
// 2647.300 us; speedup vs baseline: 1.1710x; 1.1710x over previous
//
#include <hip/hip_runtime.h>
#include <math.h>

constexpr int C96  = 96;
constexpr int HW   = 50176;     // 224*224
constexpr int W224 = 224;
constexpr int QKVN = 288;
constexpr int HID  = 384;

typedef __bf16 bf16x8 __attribute__((ext_vector_type(8)));
typedef float  f32x4  __attribute__((ext_vector_type(4)));
typedef unsigned short u16x8 __attribute__((ext_vector_type(8)));
typedef unsigned short u16x4 __attribute__((ext_vector_type(4)));

__device__ __forceinline__ float bf2f(unsigned short u) {
    return __uint_as_float(((unsigned int)u) << 16);
}
__device__ __forceinline__ unsigned short f2bf(float f) {
    unsigned int u = __float_as_uint(f);
    u = (u + 0x7fffu + ((u >> 16) & 1u)) >> 16;
    return (unsigned short)u;
}

// ---- shared 64x96 MFMA tile core (A in la[64][104], Bt in lb[96][104]) ----
__device__ __forceinline__ void zero_acc(f32x4 acc[2][3]) {
#pragma unroll
    for (int a = 0; a < 2; ++a)
#pragma unroll
        for (int b = 0; b < 3; ++b)
#pragma unroll
            for (int r = 0; r < 4; ++r) acc[a][b][r] = 0.f;
}

__device__ __forceinline__ void mfma_tile_96(const unsigned short* la, const unsigned short* lb,
                                             int wm, int wn, int l15, int quad,
                                             f32x4 acc[2][3]) {
#pragma unroll
    for (int ks = 0; ks < 3; ++ks) {
        bf16x8 a0 = *(const bf16x8*)&la[(wm*32 +      l15)*104 + ks*32 + quad*8];
        bf16x8 a1 = *(const bf16x8*)&la[(wm*32 + 16 + l15)*104 + ks*32 + quad*8];
#pragma unroll
        for (int fn = 0; fn < 3; ++fn) {
            bf16x8 bv = *(const bf16x8*)&lb[(wn*48 + fn*16 + l15)*104 + ks*32 + quad*8];
            acc[0][fn] = __builtin_amdgcn_mfma_f32_16x16x32_bf16(a0, bv, acc[0][fn], 0, 0, 0);
            acc[1][fn] = __builtin_amdgcn_mfma_f32_16x16x32_bf16(a1, bv, acc[1][fn], 0, 0, 0);
        }
    }
}

// LayerNorm over the 96 columns of each of 64 rows staged in la (in place, bf16).
__device__ __forceinline__ void ln_rows(unsigned short* la, int tid,
                                        const float* __restrict__ g,
                                        const float* __restrict__ be) {
    const int r  = tid >> 2;
    const int c0 = (tid & 3) * 24;
    float rv[24];
    float s = 0.f;
#pragma unroll
    for (int c = 0; c < 24; ++c) { rv[c] = bf2f(la[r*104 + c0 + c]); s += rv[c]; }
    s += __shfl_xor(s, 1);
    s += __shfl_xor(s, 2);
    const float mu = s * (1.f/96.f);
    float v2 = 0.f;
#pragma unroll
    for (int c = 0; c < 24; ++c) { const float d = rv[c] - mu; v2 += d*d; }
    v2 += __shfl_xor(v2, 1);
    v2 += __shfl_xor(v2, 2);
    const float rs = rsqrtf(v2 * (1.f/96.f) + 1e-5f);
#pragma unroll
    for (int c = 0; c < 24; ++c) {
        la[r*104 + c0 + c] = f2bf((rv[c] - mu) * rs * g[c0 + c] + be[c0 + c]);
    }
}

// ---- kernel 1: (transpose from NCHW fp32) + LN1 + QKV GEMM -> qkv bf16 ----
__global__ __launch_bounds__(256) void k_qkv(const float* __restrict__ x,
                                             const float* __restrict__ g,
                                             const float* __restrict__ be,
                                             const float* __restrict__ w,
                                             const float* __restrict__ bias,
                                             unsigned short* __restrict__ qkv) {
    __shared__ __attribute__((aligned(16))) unsigned short la[64*104];
    __shared__ __attribute__((aligned(16))) unsigned short lb[96*104];
    const int tid   = threadIdx.x;
    const int ncol0 = blockIdx.x * 96;
    const int row0  = blockIdx.y * 64;
    const int b     = row0 / HW;
    const int hw0   = row0 - b*HW;

    // A tile: 64 tokens x 96 ch, coalesced along hw (fp32), transposed into LDS as bf16
    for (int idx = tid; idx < 96*16; idx += 256) {
        int c = idx >> 4, t4 = (idx & 15) * 4;
        f32x4 v = *(const f32x4*)&x[(size_t)(b*C96 + c)*HW + hw0 + t4];
#pragma unroll
        for (int e = 0; e < 4; ++e) la[(t4+e)*104 + c] = f2bf(v[e]);
    }
    // Bt tile: 96x96 slice of qkv_w (fp32), transposed into LDS as bf16
    for (int idx = tid; idx < 96*24; idx += 256) {
        int k = idx / 24, n4 = (idx - k*24) * 4;
        f32x4 v = *(const f32x4*)&w[(size_t)k*QKVN + ncol0 + n4];
#pragma unroll
        for (int e = 0; e < 4; ++e) lb[(n4+e)*104 + k] = f2bf(v[e]);
    }
    __syncthreads();
    ln_rows(la, tid, g, be);
    __syncthreads();

    f32x4 acc[2][3];
    zero_acc(acc);
    const int lane = tid & 63, wv = tid >> 6;
    const int wm = wv & 1, wn = wv >> 1;
    const int l15 = lane & 15, quad = lane >> 4;
    mfma_tile_96(la, lb, wm, wn, l15, quad, acc);

    float bs[3];
#pragma unroll
    for (int fn = 0; fn < 3; ++fn) bs[fn] = bias[ncol0 + wn*48 + fn*16 + l15];
#pragma unroll
    for (int fm = 0; fm < 2; ++fm)
#pragma unroll
        for (int fn = 0; fn < 3; ++fn)
#pragma unroll
            for (int r = 0; r < 4; ++r) {
                int row = row0 + wm*32 + fm*16 + quad*4 + r;
                int col = ncol0 + wn*48 + fn*16 + l15;
                qkv[(size_t)row*QKVN + col] = f2bf(acc[fm][fn][r] + bs[fn]);
            }
}

// ---- kernel 2: windowed attention, MFMA version ----
// One block = 4 waves = 4 windows of ONE head (bias table shared per block).
// Per wave LDS region (7424 elems = 14848 B):
//   Q  [64][40] @ 0      (rows 49..63 garbage, masked downstream)
//   K  [64][40] @ 2560
//   VT [32][72] @ 5120   (V transposed, cols j>=49 zeroed)
//   P  [64][72] @ 0      (overlay of Q+K after S is in registers)
//   O  [64][40] @ 0      (overlay of P after PV)
// Block bias: bf16 [49][52] @ 4*7424.  Total 64592 B static LDS.
__global__ __launch_bounds__(256) void k_attn(const unsigned short* __restrict__ qkv,
                                              const float* __restrict__ rpb,
                                              const int* __restrict__ rel,
                                              unsigned short* __restrict__ attn_out) {
    __shared__ __attribute__((aligned(16))) unsigned short sm[4*7424 + 2600];
    const int tid  = threadIdx.x;
    const int lane = tid & 63;
    const int wave = tid >> 6;
    const int h    = blockIdx.x % 3;
    const int g    = blockIdx.x / 3;
    const int w    = g*4 + wave;
    const int b    = w >> 10;
    const int wr   = w & 1023;
    const int base_hw = (wr >> 5)*7*W224 + (wr & 31)*7;

    unsigned short* lw = sm + wave*7424;
    unsigned short* bI = sm + 4*7424;

    // bias table (block-wide, one head)
    for (int idx = tid; idx < 2401; idx += 256) {
        int i = idx / 49, j = idx - i*49;
        bI[i*52 + j] = f2bf(rpb[rel[idx]*3 + h]);
    }
    // per-wave q/k/v staging (49 tokens x 32 dims each of q,k,v for head h)
    for (int idx = lane; idx < 588; idx += 64) {
        int i = idx / 12, p = idx - i*12;
        int seg = p >> 2, part = p & 3;
        int row = b*HW + base_hw + (i/7)*W224 + (i - (i/7)*7);
        u16x8 v = *(const u16x8*)&qkv[(size_t)row*QKVN + seg*96 + h*32 + part*8];
        if (seg == 0)      *(u16x8*)&lw[i*40 + part*8] = v;
        else if (seg == 1) *(u16x8*)&lw[2560 + i*40 + part*8] = v;
        else {
            int d0 = part*8;
#pragma unroll
            for (int e = 0; e < 8; ++e) lw[5120 + (d0+e)*72 + i] = v[e];
        }
    }
    // zero VT pad columns j = 49..63 (so P==0 there can't meet inf/NaN garbage)
    for (int idx = lane; idx < 480; idx += 64) {
        int d = idx / 15, j = 49 + (idx - d*15);
        lw[5120 + d*72 + j] = 0;
    }
    __syncthreads();

    const int l15 = lane & 15, quad = lane >> 4;

    // ---- S^T = K @ Q^T : D[j][i], j=mt*16+quad*4+reg, i=nt*16+l15 ----
    f32x4 acc[4][4];
#pragma unroll
    for (int mt = 0; mt < 4; ++mt)
#pragma unroll
        for (int nt = 0; nt < 4; ++nt)
#pragma unroll
            for (int r = 0; r < 4; ++r) acc[mt][nt][r] = 0.f;
#pragma unroll
    for (int mt = 0; mt < 4; ++mt) {
        bf16x8 ak = *(const bf16x8*)&lw[2560 + (mt*16 + l15)*40 + quad*8];
#pragma unroll
        for (int nt = 0; nt < 4; ++nt) {
            bf16x8 bq = *(const bf16x8*)&lw[(nt*16 + l15)*40 + quad*8];
            acc[mt][nt] = __builtin_amdgcn_mfma_f32_16x16x32_bf16(ak, bq, acc[mt][nt], 0, 0, 0);
        }
    }

    // ---- bias + scale + mask + softmax over j (per column i), P -> LDS ----
    const float scale = 0.17677669529663687f;  // 1/sqrt(32)
#pragma unroll
    for (int nt = 0; nt < 4; ++nt) {
        const int ii = nt*16 + l15;
        const int ib = ii < 49 ? ii : 48;
        float sv[4][4];
        float mx = -1e30f;
#pragma unroll
        for (int mt = 0; mt < 4; ++mt) {
            u16x4 bb = *(const u16x4*)&bI[ib*52 + mt*16 + quad*4];
#pragma unroll
            for (int r = 0; r < 4; ++r) {
                int j = mt*16 + quad*4 + r;
                float v = acc[mt][nt][r]*scale + bf2f(bb[r]);
                v = (j < 49) ? v : -1e30f;
                sv[mt][r] = v;
                mx = fmaxf(mx, v);
            }
        }
        mx = fmaxf(mx, __shfl_xor(mx, 16));
        mx = fmaxf(mx, __shfl_xor(mx, 32));
        float sum = 0.f;
#pragma unroll
        for (int mt = 0; mt < 4; ++mt)
#pragma unroll
            for (int r = 0; r < 4; ++r) {
                float e = __expf(sv[mt][r] - mx);
                sv[mt][r] = e; sum += e;
            }
        sum += __shfl_xor(sum, 16);
        sum += __shfl_xor(sum, 32);
        float inv = 1.f / sum;
#pragma unroll
        for (int mt = 0; mt < 4; ++mt) {
            u16x4 pw;
#pragma unroll
            for (int r = 0; r < 4; ++r) pw[r] = f2bf(sv[mt][r] * inv);
            *(u16x4*)&lw[ii*72 + mt*16 + quad*4] = pw;   // P overlay on Q/K
        }
    }
    __syncthreads();

    // ---- O^T = VT @ P : D[d][i], d=mt*16+quad*4+reg, i=nt*16+l15 ----
    f32x4 acc2[2][4];
#pragma unroll
    for (int mt = 0; mt < 2; ++mt)
#pragma unroll
        for (int nt = 0; nt < 4; ++nt)
#pragma unroll
            for (int r = 0; r < 4; ++r) acc2[mt][nt][r] = 0.f;
#pragma unroll
    for (int s = 0; s < 2; ++s)
#pragma unroll
        for (int mt = 0; mt < 2; ++mt) {
            bf16x8 av = *(const bf16x8*)&lw[5120 + (mt*16 + l15)*72 + s*32 + quad*8];
#pragma unroll
            for (int nt = 0; nt < 4; ++nt) {
                bf16x8 bp = *(const bf16x8*)&lw[(nt*16 + l15)*72 + s*32 + quad*8];
                acc2[mt][nt] = __builtin_amdgcn_mfma_f32_16x16x32_bf16(av, bp, acc2[mt][nt], 0, 0, 0);
            }
        }
    __syncthreads();

    // ---- O to LDS [64][40] overlay (transpose back to [token][dim]) ----
#pragma unroll
    for (int mt = 0; mt < 2; ++mt)
#pragma unroll
        for (int nt = 0; nt < 4; ++nt) {
            int ii = nt*16 + l15;
            u16x4 o4;
#pragma unroll
            for (int r = 0; r < 4; ++r) o4[r] = f2bf(acc2[mt][nt][r]);
            *(u16x4*)&lw[ii*40 + mt*16 + quad*4] = o4;
        }
    __syncthreads();

    // ---- vectorized global write ----
    for (int idx = lane; idx < 196; idx += 64) {
        int t = idx >> 2, c8 = (idx & 3)*8;
        int row = b*HW + base_hw + (t/7)*W224 + (t - (t/7)*7);
        *(u16x8*)&attn_out[(size_t)row*C96 + h*32 + c8] = *(const u16x8*)&lw[t*40 + c8];
    }
}

// ---- kernel 3: proj GEMM + fp32 shortcut residual (from x, NCHW) -> x2 fp32 ----
__global__ __launch_bounds__(256) void k_proj(const unsigned short* __restrict__ ain,
                                              const float* __restrict__ w,
                                              const float* __restrict__ bias,
                                              const float* __restrict__ x,
                                              float* __restrict__ x2) {
    __shared__ __attribute__((aligned(16))) unsigned short la[64*104];
    __shared__ __attribute__((aligned(16))) unsigned short lb[96*104];
    const int tid  = threadIdx.x;
    const int row0 = blockIdx.x * 64;
    const int b    = row0 / HW;
    const int hw0  = row0 - b*HW;

    for (int idx = tid; idx < 64*12; idx += 256) {
        int i = idx / 12, c8 = (idx - i*12) * 8;
        *(u16x8*)&la[i*104 + c8] = *(const u16x8*)&ain[(size_t)(row0+i)*C96 + c8];
    }
    for (int idx = tid; idx < 96*24; idx += 256) {
        int k = idx / 24, n4 = (idx - k*24) * 4;
        f32x4 v = *(const f32x4*)&w[(size_t)k*C96 + n4];
#pragma unroll
        for (int e = 0; e < 4; ++e) lb[(n4+e)*104 + k] = f2bf(v[e]);
    }
    __syncthreads();

    f32x4 acc[2][3];
    zero_acc(acc);
    const int lane = tid & 63, wv = tid >> 6;
    const int wm = wv & 1, wn = wv >> 1;
    const int l15 = lane & 15, quad = lane >> 4;
    mfma_tile_96(la, lb, wm, wn, l15, quad, acc);

    float bs[3];
#pragma unroll
    for (int fn = 0; fn < 3; ++fn) bs[fn] = bias[wn*48 + fn*16 + l15];
#pragma unroll
    for (int fm = 0; fm < 2; ++fm)
#pragma unroll
        for (int fn = 0; fn < 3; ++fn)
#pragma unroll
            for (int r = 0; r < 4; ++r) {
                int i   = wm*32 + fm*16 + quad*4 + r;
                int col = wn*48 + fn*16 + l15;
                float v = acc[fm][fn][r] + bs[fn]
                        + x[(size_t)(b*C96 + col)*HW + hw0 + i];
                x2[(size_t)(row0+i)*C96 + col] = v;
            }
}

// ---- kernel 4: LN2 + MLP fc1 + exact GELU -> hbuf bf16 ----
__global__ __launch_bounds__(256) void k_mlp1(const float* __restrict__ x2,
                                              const float* __restrict__ g,
                                              const float* __restrict__ be,
                                              const float* __restrict__ w,
                                              const float* __restrict__ bias,
                                              unsigned short* __restrict__ hbuf) {
    __shared__ __attribute__((aligned(16))) unsigned short la[64*104];
    __shared__ __attribute__((aligned(16))) unsigned short lb[96*104];
    const int tid   = threadIdx.x;
    const int ncol0 = blockIdx.x * 96;
    const int row0  = blockIdx.y * 64;

    for (int idx = tid; idx < 64*24; idx += 256) {
        int i = idx / 24, c4 = (idx - i*24) * 4;
        f32x4 v = *(const f32x4*)&x2[(size_t)(row0+i)*C96 + c4];
#pragma unroll
        for (int e = 0; e < 4; ++e) la[i*104 + c4 + e] = f2bf(v[e]);
    }
    for (int idx = tid; idx < 96*24; idx += 256) {
        int k = idx / 24, n4 = (idx - k*24) * 4;
        f32x4 v = *(const f32x4*)&w[(size_t)k*HID + ncol0 + n4];
#pragma unroll
        for (int e = 0; e < 4; ++e) lb[(n4+e)*104 + k] = f2bf(v[e]);
    }
    __syncthreads();
    ln_rows(la, tid, g, be);
    __syncthreads();

    f32x4 acc[2][3];
    zero_acc(acc);
    const int lane = tid & 63, wv = tid >> 6;
    const int wm = wv & 1, wn = wv >> 1;
    const int l15 = lane & 15, quad = lane >> 4;
    mfma_tile_96(la, lb, wm, wn, l15, quad, acc);

    float bs[3];
#pragma unroll
    for (int fn = 0; fn < 3; ++fn) bs[fn] = bias[ncol0 + wn*48 + fn*16 + l15];
#pragma unroll
    for (int fm = 0; fm < 2; ++fm)
#pragma unroll
        for (int fn = 0; fn < 3; ++fn)
#pragma unroll
            for (int r = 0; r < 4; ++r) {
                int row = row0 + wm*32 + fm*16 + quad*4 + r;
                int col = ncol0 + wn*48 + fn*16 + l15;
                float v = acc[fm][fn][r] + bs[fn];
                v = 0.5f * v * (1.f + erff(v * 0.70710678118654752f));
                hbuf[(size_t)row*HID + col] = f2bf(v);
            }
}

// ---- kernel 5: MLP fc2 (K=384) + fp32 residual + transposed NCHW fp32 write ----
__global__ __launch_bounds__(256) void k_mlp2(const unsigned short* __restrict__ hbuf,
                                              const float* __restrict__ w,
                                              const float* __restrict__ bias,
                                              const float* __restrict__ x2,
                                              float* __restrict__ out) {
    __shared__ __attribute__((aligned(16))) char smem[(64 + 96) * 104 * 2];
    unsigned short* la = (unsigned short*)smem;
    unsigned short* lb = (unsigned short*)(smem + 64*104*2);
    const int tid  = threadIdx.x;
    const int row0 = blockIdx.x * 64;
    const int b    = row0 / HW;
    const int hw0  = row0 - b*HW;

    f32x4 acc[2][3];
    zero_acc(acc);
    const int lane = tid & 63, wv = tid >> 6;
    const int wm = wv & 1, wn = wv >> 1;
    const int l15 = lane & 15, quad = lane >> 4;

    for (int kb = 0; kb < 4; ++kb) {
        if (kb) __syncthreads();
        for (int idx = tid; idx < 64*12; idx += 256) {
            int i = idx / 12, c8 = (idx - i*12) * 8;
            *(u16x8*)&la[i*104 + c8] =
                *(const u16x8*)&hbuf[(size_t)(row0+i)*HID + kb*96 + c8];
        }
        for (int idx = tid; idx < 96*24; idx += 256) {
            int k = idx / 24, n4 = (idx - k*24) * 4;
            f32x4 v = *(const f32x4*)&w[(size_t)(kb*96 + k)*C96 + n4];
#pragma unroll
            for (int e = 0; e < 4; ++e) lb[(n4+e)*104 + k] = f2bf(v[e]);
        }
        __syncthreads();
        mfma_tile_96(la, lb, wm, wn, l15, quad, acc);
    }
    __syncthreads();

    // stage fp32 results in LDS (reuse smem as float[64][100]), then coalesced write
    float* lf = (float*)smem;
    float bs[3];
#pragma unroll
    for (int fn = 0; fn < 3; ++fn) bs[fn] = bias[wn*48 + fn*16 + l15];
#pragma unroll
    for (int fm = 0; fm < 2; ++fm)
#pragma unroll
        for (int fn = 0; fn < 3; ++fn)
#pragma unroll
            for (int r = 0; r < 4; ++r) {
                int i   = wm*32 + fm*16 + quad*4 + r;
                int col = wn*48 + fn*16 + l15;
                lf[i*100 + col] = acc[fm][fn][r] + bs[fn]
                                + x2[(size_t)(row0+i)*C96 + col];
            }
    __syncthreads();
    // transposed coalesced fp32 write to NCHW
    for (int idx = tid; idx < 96*16; idx += 256) {
        int c = idx >> 4, t4 = (idx & 15) * 4;
        f32x4 v;
#pragma unroll
        for (int e = 0; e < 4; ++e) v[e] = lf[(t4+e)*100 + c];
        *(f32x4*)&out[(size_t)(b*C96 + c)*HW + hw0 + t4] = v;
    }
}

extern "C" void kernel_launch(void* const* d_in, const int* in_sizes, int n_in,
                              void* d_out, int out_size, void* d_ws, size_t ws_size,
                              hipStream_t stream) {
    (void)in_sizes; (void)n_in; (void)out_size;
    const float* x      = (const float*)d_in[0];
    const float* ln1_g  = (const float*)d_in[1];
    const float* ln1_b  = (const float*)d_in[2];
    const float* qkv_w  = (const float*)d_in[3];
    const float* qkv_b  = (const float*)d_in[4];
    const float* rpb    = (const float*)d_in[5];
    const float* proj_w = (const float*)d_in[6];
    const float* proj_b = (const float*)d_in[7];
    const float* ln2_g  = (const float*)d_in[8];
    const float* ln2_b  = (const float*)d_in[9];
    const float* mlp_w1 = (const float*)d_in[10];
    const float* mlp_b1 = (const float*)d_in[11];
    const float* mlp_w2 = (const float*)d_in[12];
    const float* mlp_b2 = (const float*)d_in[13];
    const int*   rel    = (const int*)d_in[14];
    float* out = (float*)d_out;

    // per-image workspace regions:
    //   R0: qkv bf16 (HW*288*2) reused as mlp hidden bf16 (HW*384*2) -> HW*384*2
    //   R1: attn_out bf16 (HW*96*2)
    //   R2: x2 fp32 (HW*96*4)
    constexpr size_t R0 = (size_t)HW * HID * 2;   // 38,535,168
    constexpr size_t R1 = (size_t)HW * C96 * 2;   //  9,633,792
    constexpr size_t R2 = (size_t)HW * C96 * 4;   // 19,267,584
    constexpr size_t PER_IMG = R0 + R1 + R2;      // 67,436,544

    int nimg = (int)(ws_size / PER_IMG);
    if (nimg < 1)  nimg = 1;
    if (nimg > 16) nimg = 16;

    char* ws = (char*)d_ws;
    unsigned short* qkvb  = (unsigned short*)ws;                          // also hbuf
    unsigned short* attnb = (unsigned short*)(ws + (size_t)nimg * R0);
    float*          x2b   = (float*)(ws + (size_t)nimg * (R0 + R1));

    for (int c0 = 0; c0 < 16; c0 += nimg) {
        int m = 16 - c0 < nimg ? 16 - c0 : nimg;
        const float* xc = x + (size_t)c0 * C96 * HW;
        float* outc = out + (size_t)c0 * C96 * HW;
        const int MBc = m * (HW / 64);   // 784 row-blocks per image

        k_qkv <<<dim3(3, MBc), 256, 0, stream>>>(xc, ln1_g, ln1_b, qkv_w, qkv_b, qkvb);
        k_attn<<<m * 768,      256, 0, stream>>>(qkvb, rpb, rel, attnb);
        k_proj<<<MBc,          256, 0, stream>>>(attnb, proj_w, proj_b, xc, x2b);
        k_mlp1<<<dim3(4, MBc), 256, 0, stream>>>(x2b, ln2_g, ln2_b, mlp_w1, mlp_b1, qkvb);
        k_mlp2<<<MBc,          256, 0, stream>>>(qkvb, mlp_w2, mlp_b2, x2b, outc);
    }
}